// Round 5
// baseline (136.874 us; speedup 1.0000x reference)
//
#include <hip/hip_runtime.h>

#define B 4
#define V 8192
#define F 16384
#define P 4
#define E 2048
#define NPAIR 16

// ws layout (float indices)
#define WS_PTS   0         // NPAIR*V float4 (px,py,|p|^2,0) = 524288 floats
#define WS_ER    524288    // NPAIR*E float4 (ex,ey,|e|^2,0) = 131072 floats
#define WS_VMIN  655360    // NPAIR*V uint-min bits (d2 >= 0) = 131072
#define WS_EMIN  786432    // NPAIR*E uint-min bits = 32768
#define WS_LSQP  819200    // 128 per-block lsq partials
#define WS_VOLPX 819328    // 256 per-block vol-x partials
#define WS_VOLPY 819584    // 256 per-block vol-y partials (end 819840 = 3.28 MB)

#define INFBITS 0x7F800000u

__device__ __forceinline__ float block_sum(float v, float* sred) {
    #pragma unroll
    for (int off = 32; off; off >>= 1) v += __shfl_down(v, off, 64);
    int w = threadIdx.x >> 6, l = threadIdx.x & 63;
    if (l == 0) sred[w] = v;
    __syncthreads();
    float r = 0.f;
    if (threadIdx.x == 0) {
        r = sred[0];
        for (int i = 1; i < ((int)blockDim.x >> 6); ++i) r += sred[i];
    }
    __syncthreads();
    return r;  // valid on thread 0 only
}

__device__ __forceinline__ float facevol(const float* __restrict__ vb,
                                         int i0, int i1, int i2) {
    float a0 = vb[i0 * 3], a1 = vb[i0 * 3 + 1], a2 = vb[i0 * 3 + 2];
    float b0 = vb[i1 * 3], b1 = vb[i1 * 3 + 1], b2 = vb[i1 * 3 + 2];
    float c0 = vb[i2 * 3], c1 = vb[i2 * 3 + 1], c2 = vb[i2 * 3 + 2];
    float cx = a1 * b2 - a2 * b1;
    float cy = a2 * b0 - a0 * b2;
    float cz = a0 * b1 - a1 * b0;
    return (cx * c0 + cy * c1 + cz * c2) * (1.0f / 6.0f);
}

// Fused: [0,128) proj+lsq, [128,384) volumes, [384,896) init mins + build ER.
// No cross-range dependencies; accumulators replaced by per-block partial slots.
__global__ void __launch_bounds__(256) k_pre(const float* __restrict__ xs,
                                             const float* __restrict__ y,
                                             const float* __restrict__ pm,
                                             const float* __restrict__ em,
                                             const int* __restrict__ faces,
                                             float* __restrict__ ws) {
    __shared__ float spm[48];
    __shared__ float sred[4];
    int tid = threadIdx.x;
    int blk = blockIdx.x;

    if (blk < 128) {                          // ---- projection + lsq
        if (tid < 48) spm[tid] = pm[tid];
        __syncthreads();
        int b = blk >> 5;                     // 32 blocks per batch
        int v = ((blk & 31) << 8) + tid;
        size_t base = ((size_t)b * V + v) * 3;
        float y0 = y[base], y1 = y[base + 1], y2 = y[base + 2];
        float x0 = xs[base], x1 = xs[base + 1], x2 = xs[base + 2];
        float d0 = x0 - y0, d1 = x1 - y1, d2 = x2 - y2;
        float lsq = d0 * d0 + d1 * d1 + d2 * d2;

        float4* pts = (float4*)(ws + WS_PTS);
        #pragma unroll
        for (int p = 0; p < P; ++p) {
            const float* m = spm + p * 12;
            float xw = m[0] * y0 + m[1] * y1 + m[2]  * y2 + m[3];
            float yw = m[4] * y0 + m[5] * y1 + m[6]  * y2 + m[7];
            float w  = m[8] * y0 + m[9] * y1 + m[10] * y2 + m[11];
            float px = xw / w, py = yw / w;
            pts[(size_t)(b * P + p) * V + v] = make_float4(px, py, px * px + py * py, 0.f);
        }
        float s = block_sum(lsq, sred);
        if (tid == 0) ws[WS_LSQP + blk] = s;
    } else if (blk < 384) {                   // ---- face volumes
        int blk2 = blk - 128;
        int b = blk2 >> 6;                    // 64 blocks per batch
        int f = ((blk2 & 63) << 8) + tid;
        size_t fb = ((size_t)b * F + f) * 3;
        int i0 = faces[fb], i1 = faces[fb + 1], i2 = faces[fb + 2];
        const float* xb = xs + (size_t)b * V * 3;
        const float* yb = y  + (size_t)b * V * 3;
        float sx = block_sum(facevol(xb, i0, i1, i2), sred);
        float sy = block_sum(facevol(yb, i0, i1, i2), sred);
        if (tid == 0) { ws[WS_VOLPX + blk2] = sx; ws[WS_VOLPY + blk2] = sy; }
    } else {                                  // ---- init mins, build ER
        int i = (blk - 384) * 256 + tid;      // [0, 131072)
        ((unsigned*)(ws + WS_VMIN))[i] = INFBITS;
        if (i < NPAIR * E) {
            ((unsigned*)(ws + WS_EMIN))[i] = INFBITS;
            float2 e = ((const float2*)em)[i];
            ((float4*)(ws + WS_ER))[i] = make_float4(e.x, e.y, e.x * e.x + e.y * e.y, 0.f);
        }
    }
}

// Fused chamfer, 1024 blocks (4/CU):
//  [0,512): min over e for each v — thread owns 8 v's, edges stream via LDS broadcast
//  [512,1024): min over v for each e — thread owns 8 e's, points stream via LDS broadcast
__global__ void __launch_bounds__(256) k_cham(float* __restrict__ ws) {
    __shared__ float4 sbuf[256];              // 4 KB streamed chunk
    int tid = threadIdx.x;
    int blk = blockIdx.x;

    if (blk < 512) {                          // ---- cham_x
        int pair = blk >> 5;
        int vch = (blk >> 3) & 3;
        int ech = blk & 7;
        sbuf[tid] = ((const float4*)(ws + WS_ER))[(size_t)pair * E + ech * 256 + tid];

        const float4* pts = (const float4*)(ws + WS_PTS) + (size_t)pair * V + vch * 2048 + tid;
        float px2[8], py2[8], pz[8], mn[8];
        #pragma unroll
        for (int k = 0; k < 8; ++k) {
            float4 p = pts[k * 256];
            px2[k] = -2.f * p.x; py2[k] = -2.f * p.y; pz[k] = p.z;
            mn[k] = 3.4e38f;
        }
        __syncthreads();
        #pragma unroll 4
        for (int i = 0; i < 256; ++i) {
            float4 e = sbuf[i];               // wave-uniform broadcast
            #pragma unroll
            for (int k = 0; k < 8; ++k)
                mn[k] = fminf(mn[k], fmaf(px2[k], e.x, fmaf(py2[k], e.y, e.z)));
        }
        unsigned* vmin = (unsigned*)(ws + WS_VMIN) + (size_t)pair * V + vch * 2048 + tid;
        #pragma unroll
        for (int k = 0; k < 8; ++k)
            atomicMin(vmin + k * 256, __float_as_uint(mn[k] + pz[k]));
    } else {                                  // ---- cham_y
        int blk2 = blk - 512;
        int pair = blk2 >> 5;
        int vch = blk2 & 31;
        sbuf[tid] = ((const float4*)(ws + WS_PTS))[(size_t)pair * V + vch * 256 + tid];

        const float4* er = (const float4*)(ws + WS_ER) + (size_t)pair * E + tid;
        float ex2[8], ey2[8], ez[8], mn[8];
        #pragma unroll
        for (int k = 0; k < 8; ++k) {
            float4 e = er[k * 256];
            ex2[k] = -2.f * e.x; ey2[k] = -2.f * e.y; ez[k] = e.z;
            mn[k] = 3.4e38f;
        }
        __syncthreads();
        #pragma unroll 4
        for (int i = 0; i < 256; ++i) {
            float4 p = sbuf[i];               // wave-uniform broadcast
            #pragma unroll
            for (int k = 0; k < 8; ++k)
                mn[k] = fminf(mn[k], fmaf(ex2[k], p.x, fmaf(ey2[k], p.y, p.z)));
        }
        unsigned* emin = (unsigned*)(ws + WS_EMIN) + (size_t)pair * E + tid;
        #pragma unroll
        for (int k = 0; k < 8; ++k)
            atomicMin(emin + k * 256, __float_as_uint(mn[k] + ez[k]));
    }
}

// 4 blocks, one per batch: reduce mins + partials, write out[b]
__global__ void __launch_bounds__(256) k_fin(float* __restrict__ ws,
                                             float* __restrict__ out) {
    __shared__ float sred[4];
    int tid = threadIdx.x;
    int b = blockIdx.x;
    const float* vmin = ws + WS_VMIN;
    const float* emin = ws + WS_EMIN;

    float sv = 0.f, se = 0.f;
    #pragma unroll
    for (int p = 0; p < P; ++p) {
        size_t vb = (size_t)(b * P + p) * V;
        for (int i = tid; i < V; i += 256) sv += vmin[vb + i];
        size_t eb = (size_t)(b * P + p) * E;
        for (int i = tid; i < E; i += 256) se += emin[eb + i];
    }
    float cham = block_sum(sv * (1.0f / (V * P)) + se * (1.0f / (E * P)), sred);
    float volx = block_sum((tid < 64) ? ws[WS_VOLPX + b * 64 + tid] : 0.f, sred);
    float voly = block_sum((tid < 64) ? ws[WS_VOLPY + b * 64 + tid] : 0.f, sred);
    float lsq  = block_sum((tid < 32) ? ws[WS_LSQP  + b * 32 + tid] : 0.f, sred);
    if (tid == 0) {
        float dv = fabsf(voly) - fabsf(volx);
        out[b] = cham + lsq + dv * dv;
    }
}

extern "C" void kernel_launch(void* const* d_in, const int* in_sizes, int n_in,
                              void* d_out, int out_size, void* d_ws, size_t ws_size,
                              hipStream_t stream) {
    const float* xs    = (const float*)d_in[0];
    const float* y     = (const float*)d_in[1];
    const float* pm    = (const float*)d_in[2];
    const float* em    = (const float*)d_in[3];
    const int*   faces = (const int*)d_in[4];
    float* ws  = (float*)d_ws;
    float* out = (float*)d_out;

    hipLaunchKernelGGL(k_pre,  dim3(896),  dim3(256), 0, stream, xs, y, pm, em, faces, ws);
    hipLaunchKernelGGL(k_cham, dim3(1024), dim3(256), 0, stream, ws);
    hipLaunchKernelGGL(k_fin,  dim3(4),    dim3(256), 0, stream, ws, out);
}

// Round 6
// 110.108 us; speedup vs baseline: 1.2431x; 1.2431x over previous
//
#include <hip/hip_runtime.h>

#define B 4
#define V 8192
#define F 16384
#define P 4
#define E 2048
#define NPAIR 16

// ws layout (float indices)
#define WS_PTS   0         // NPAIR*V float4 (px,py,|p|^2,0) = 524288 floats
#define WS_ER    524288    // NPAIR*E float4 (ex,ey,|e|^2,0) = 131072 floats
#define WS_VMIN  655360    // NPAIR*V uint-min bits (d2 >= 0) = 131072
#define WS_EMIN  786432    // NPAIR*E uint-min bits = 32768
#define WS_LSQP  819200    // 128 per-block lsq partials
#define WS_VOLPX 819328    // 256 per-block vol-x partials
#define WS_VOLPY 819584    // 256 per-block vol-y partials
#define WS_CX    819840    // NPAIR chamfer-x accum (zeroed in k_pre)
#define WS_CY    819856    // NPAIR chamfer-y accum (end 819872 = 3.28 MB)

#define INFBITS 0x7F800000u

__device__ __forceinline__ float block_sum(float v, float* sred) {
    #pragma unroll
    for (int off = 32; off; off >>= 1) v += __shfl_down(v, off, 64);
    int w = threadIdx.x >> 6, l = threadIdx.x & 63;
    if (l == 0) sred[w] = v;
    __syncthreads();
    float r = 0.f;
    if (threadIdx.x == 0) {
        r = sred[0];
        for (int i = 1; i < ((int)blockDim.x >> 6); ++i) r += sred[i];
    }
    __syncthreads();
    return r;  // valid on thread 0 only
}

__device__ __forceinline__ float facevol(const float* __restrict__ vb,
                                         int i0, int i1, int i2) {
    float a0 = vb[i0 * 3], a1 = vb[i0 * 3 + 1], a2 = vb[i0 * 3 + 2];
    float b0 = vb[i1 * 3], b1 = vb[i1 * 3 + 1], b2 = vb[i1 * 3 + 2];
    float c0 = vb[i2 * 3], c1 = vb[i2 * 3 + 1], c2 = vb[i2 * 3 + 2];
    float cx = a1 * b2 - a2 * b1;
    float cy = a2 * b0 - a0 * b2;
    float cz = a0 * b1 - a1 * b0;
    return (cx * c0 + cy * c1 + cz * c2) * (1.0f / 6.0f);
}

// Fused: [0,128) proj+lsq, [128,384) volumes, [384,896) init mins + build ER.
__global__ void __launch_bounds__(256) k_pre(const float* __restrict__ xs,
                                             const float* __restrict__ y,
                                             const float* __restrict__ pm,
                                             const float* __restrict__ em,
                                             const int* __restrict__ faces,
                                             float* __restrict__ ws) {
    __shared__ float spm[48];
    __shared__ float sred[4];
    int tid = threadIdx.x;
    int blk = blockIdx.x;

    if (blk < 128) {                          // ---- projection + lsq
        if (tid < 48) spm[tid] = pm[tid];
        __syncthreads();
        int b = blk >> 5;                     // 32 blocks per batch
        int v = ((blk & 31) << 8) + tid;
        size_t base = ((size_t)b * V + v) * 3;
        float y0 = y[base], y1 = y[base + 1], y2 = y[base + 2];
        float x0 = xs[base], x1 = xs[base + 1], x2 = xs[base + 2];
        float d0 = x0 - y0, d1 = x1 - y1, d2 = x2 - y2;
        float lsq = d0 * d0 + d1 * d1 + d2 * d2;

        float4* pts = (float4*)(ws + WS_PTS);
        #pragma unroll
        for (int p = 0; p < P; ++p) {
            const float* m = spm + p * 12;
            float xw = m[0] * y0 + m[1] * y1 + m[2]  * y2 + m[3];
            float yw = m[4] * y0 + m[5] * y1 + m[6]  * y2 + m[7];
            float w  = m[8] * y0 + m[9] * y1 + m[10] * y2 + m[11];
            float px = xw / w, py = yw / w;
            pts[(size_t)(b * P + p) * V + v] = make_float4(px, py, px * px + py * py, 0.f);
        }
        float s = block_sum(lsq, sred);
        if (tid == 0) ws[WS_LSQP + blk] = s;
    } else if (blk < 384) {                   // ---- face volumes
        int blk2 = blk - 128;
        int b = blk2 >> 6;                    // 64 blocks per batch
        int f = ((blk2 & 63) << 8) + tid;
        size_t fb = ((size_t)b * F + f) * 3;
        int i0 = faces[fb], i1 = faces[fb + 1], i2 = faces[fb + 2];
        const float* xb = xs + (size_t)b * V * 3;
        const float* yb = y  + (size_t)b * V * 3;
        float sx = block_sum(facevol(xb, i0, i1, i2), sred);
        float sy = block_sum(facevol(yb, i0, i1, i2), sred);
        if (tid == 0) { ws[WS_VOLPX + blk2] = sx; ws[WS_VOLPY + blk2] = sy; }
    } else {                                  // ---- init mins, build ER, zero accums
        int i = (blk - 384) * 256 + tid;      // [0, 131072)
        ((unsigned*)(ws + WS_VMIN))[i] = INFBITS;
        if (i < NPAIR * E) {
            ((unsigned*)(ws + WS_EMIN))[i] = INFBITS;
            float2 e = ((const float2*)em)[i];
            ((float4*)(ws + WS_ER))[i] = make_float4(e.x, e.y, e.x * e.x + e.y * e.y, 0.f);
        }
        if (i < 32) ws[WS_CX + i] = 0.f;      // CX[16] + CY[16]
    }
}

// Fused chamfer, 1024 blocks (4/CU):
//  [0,512): min over e for each v — thread owns 8 v's, edges stream via LDS broadcast
//  [512,1024): min over v for each e — thread owns 8 e's, points stream via LDS broadcast
__global__ void __launch_bounds__(256) k_cham(float* __restrict__ ws) {
    __shared__ float4 sbuf[256];              // 4 KB streamed chunk
    int tid = threadIdx.x;
    int blk = blockIdx.x;

    if (blk < 512) {                          // ---- cham_x
        int pair = blk >> 5;
        int vch = (blk >> 3) & 3;
        int ech = blk & 7;
        sbuf[tid] = ((const float4*)(ws + WS_ER))[(size_t)pair * E + ech * 256 + tid];

        const float4* pts = (const float4*)(ws + WS_PTS) + (size_t)pair * V + vch * 2048 + tid;
        float px2[8], py2[8], pz[8], mn[8];
        #pragma unroll
        for (int k = 0; k < 8; ++k) {
            float4 p = pts[k * 256];
            px2[k] = -2.f * p.x; py2[k] = -2.f * p.y; pz[k] = p.z;
            mn[k] = 3.4e38f;
        }
        __syncthreads();
        #pragma unroll 4
        for (int i = 0; i < 256; ++i) {
            float4 e = sbuf[i];               // wave-uniform broadcast
            #pragma unroll
            for (int k = 0; k < 8; ++k)
                mn[k] = fminf(mn[k], fmaf(px2[k], e.x, fmaf(py2[k], e.y, e.z)));
        }
        unsigned* vmin = (unsigned*)(ws + WS_VMIN) + (size_t)pair * V + vch * 2048 + tid;
        #pragma unroll
        for (int k = 0; k < 8; ++k)
            atomicMin(vmin + k * 256, __float_as_uint(mn[k] + pz[k]));
    } else {                                  // ---- cham_y
        int blk2 = blk - 512;
        int pair = blk2 >> 5;
        int vch = blk2 & 31;
        sbuf[tid] = ((const float4*)(ws + WS_PTS))[(size_t)pair * V + vch * 256 + tid];

        const float4* er = (const float4*)(ws + WS_ER) + (size_t)pair * E + tid;
        float ex2[8], ey2[8], ez[8], mn[8];
        #pragma unroll
        for (int k = 0; k < 8; ++k) {
            float4 e = er[k * 256];
            ex2[k] = -2.f * e.x; ey2[k] = -2.f * e.y; ez[k] = e.z;
            mn[k] = 3.4e38f;
        }
        __syncthreads();
        #pragma unroll 4
        for (int i = 0; i < 256; ++i) {
            float4 p = sbuf[i];               // wave-uniform broadcast
            #pragma unroll
            for (int k = 0; k < 8; ++k)
                mn[k] = fminf(mn[k], fmaf(ex2[k], p.x, fmaf(ey2[k], p.y, p.z)));
        }
        unsigned* emin = (unsigned*)(ws + WS_EMIN) + (size_t)pair * E + tid;
        #pragma unroll
        for (int k = 0; k < 8; ++k)
            atomicMin(emin + k * 256, __float_as_uint(mn[k] + ez[k]));
    }
}

// 640 blocks, wide: [0,512) sum VMIN/V into CX, [512,640) sum EMIN/E into CY
__global__ void __launch_bounds__(256) k_red(float* __restrict__ ws) {
    __shared__ float sred[4];
    int tid = threadIdx.x;
    int blk = blockIdx.x;
    float val;
    float* dst;
    if (blk < 512) {
        int idx = blk * 256 + tid;
        val = ws[WS_VMIN + idx] * (1.0f / V);
        dst = ws + WS_CX + (blk >> 5);
    } else {
        int idx = (blk - 512) * 256 + tid;
        val = ws[WS_EMIN + idx] * (1.0f / E);
        dst = ws + WS_CY + ((blk - 512) >> 3);
    }
    float s = block_sum(val, sred);
    if (tid == 0) atomicAdd(dst, s);
}

// 4 blocks, one per batch: combine accums + partial slots, write out[b]
__global__ void __launch_bounds__(256) k_out(float* __restrict__ ws,
                                             float* __restrict__ out) {
    __shared__ float sred[4];
    int tid = threadIdx.x;
    int b = blockIdx.x;
    float c = (tid < P) ? (ws[WS_CX + b * P + tid] + ws[WS_CY + b * P + tid]) : 0.f;
    float cham = block_sum(c, sred);
    float volx = block_sum((tid < 64) ? ws[WS_VOLPX + b * 64 + tid] : 0.f, sred);
    float voly = block_sum((tid < 64) ? ws[WS_VOLPY + b * 64 + tid] : 0.f, sred);
    float lsq  = block_sum((tid < 32) ? ws[WS_LSQP  + b * 32 + tid] : 0.f, sred);
    if (tid == 0) {
        float dv = fabsf(voly) - fabsf(volx);
        out[b] = cham * (1.0f / P) + lsq + dv * dv;
    }
}

extern "C" void kernel_launch(void* const* d_in, const int* in_sizes, int n_in,
                              void* d_out, int out_size, void* d_ws, size_t ws_size,
                              hipStream_t stream) {
    const float* xs    = (const float*)d_in[0];
    const float* y     = (const float*)d_in[1];
    const float* pm    = (const float*)d_in[2];
    const float* em    = (const float*)d_in[3];
    const int*   faces = (const int*)d_in[4];
    float* ws  = (float*)d_ws;
    float* out = (float*)d_out;

    hipLaunchKernelGGL(k_pre,  dim3(896),  dim3(256), 0, stream, xs, y, pm, em, faces, ws);
    hipLaunchKernelGGL(k_cham, dim3(1024), dim3(256), 0, stream, ws);
    hipLaunchKernelGGL(k_red,  dim3(640),  dim3(256), 0, stream, ws);
    hipLaunchKernelGGL(k_out,  dim3(4),    dim3(256), 0, stream, ws, out);
}